// Round 1
// baseline (249.110 us; speedup 1.0000x reference)
//
#include <hip/hip_runtime.h>
#include <hip/hip_bf16.h>
#include <stdint.h>

typedef unsigned short u16;
typedef short bf16x8 __attribute__((ext_vector_type(8)));
typedef float f32x4 __attribute__((ext_vector_type(4)));

#define C_IN 768
#define AHS 384
#define NH 6
#define HD 64
#define KK9 9
#define BSEQ 2048
#define MTOT 8192

__device__ __forceinline__ float b2f(u16 u){
  union { unsigned u; float f; } v; v.u = ((unsigned)u) << 16; return v.f;
}
__device__ __forceinline__ u16 f2b(float f){
  union { float f; unsigned u; } v; v.f = f;
  unsigned r = (v.u + 0x7FFFu + ((v.u >> 16) & 1u)) >> 16;
  return (u16)r;
}
__device__ __forceinline__ void gload_lds16(const void* g, void* l){
  __builtin_amdgcn_global_load_lds((const __attribute__((address_space(1))) unsigned int*)g,
                                   (__attribute__((address_space(3))) unsigned int*)l, 16, 0, 0);
}

// ---------------- transpose + cast f32[R][C] -> bf16[C][R] ----------------
__global__ void k_transpose_cast(const float* __restrict__ src, u16* __restrict__ dst, int R, int C){
  __shared__ float t[32][33];
  int r0 = blockIdx.x*32, c0 = blockIdx.y*32;
  int tx = threadIdx.x, ty = threadIdx.y;
  #pragma unroll
  for (int j=0;j<4;j++){
    int r = r0 + ty + j*8, c = c0 + tx;
    t[ty+j*8][tx] = (r<R && c<C) ? src[(size_t)r*C + c] : 0.f;
  }
  __syncthreads();
  #pragma unroll
  for (int j=0;j<4;j++){
    int c = c0 + ty + j*8, r = r0 + tx;
    if (r<R && c<C) dst[(size_t)c*R + r] = f2b(t[tx][ty+j*8]);
  }
}

// ---------------- X cast + depthwise conv (SAME, per batch) ----------------
__global__ __launch_bounds__(192) void k_prep_x(const float* __restrict__ X, const float* __restrict__ dwk,
                          u16* __restrict__ Xbf, u16* __restrict__ DWbf){
  int blk = blockIdx.x; int b = blk>>11; int s = blk&2047;
  int c0 = threadIdx.x*4;
  size_t base = (size_t)blk*C_IN + c0;
  float4 xc = *(const float4*)(X + base);
  *(ushort4*)(Xbf + base) = make_ushort4(f2b(xc.x), f2b(xc.y), f2b(xc.z), f2b(xc.w));
  float a0=0.f,a1=0.f,a2=0.f,a3=0.f;
  #pragma unroll
  for (int k=0;k<KK9;k++){
    int ss = s + k - 4;
    if ((unsigned)ss < 2048u){
      float4 xv = *(const float4*)(X + ((size_t)((b<<11)+ss)*C_IN + c0));
      float4 wv = *(const float4*)(dwk + k*C_IN + c0);
      a0 += xv.x*wv.x; a1 += xv.y*wv.y; a2 += xv.z*wv.z; a3 += xv.w*wv.w;
    }
  }
  *(ushort4*)(DWbf + base) = make_ushort4(f2b(a0), f2b(a1), f2b(a2), f2b(a3));
}

// ---------------- 5-way fused projection GEMM: [8192,768]x[768,384] ----------------
// z: 0=Q 1=K 2=V(-> transposed Vt[bh][d][s]) 3=CO 4=KeyConv(A=DW, B=pw)
__global__ __launch_bounds__(256) void k_gemm5(
    const u16* __restrict__ Xbf, const u16* __restrict__ DWbf,
    const u16* __restrict__ WtQ, const u16* __restrict__ WtK, const u16* __restrict__ WtV,
    const u16* __restrict__ WtCO, const u16* __restrict__ WtPW,
    const float* __restrict__ bq, const float* __restrict__ bk_, const float* __restrict__ bv,
    const float* __restrict__ bco, const float* __restrict__ bcv,
    u16* __restrict__ Qo, u16* __restrict__ Ko, u16* __restrict__ Vt,
    u16* __restrict__ COo, u16* __restrict__ KCo)
{
  __shared__ char smem[32768];
  int tid = threadIdx.x, l = tid&63, w = tid>>6;
  int g = l>>4, c = l&15;
  int wr = w>>1, wc = w&1;
  int mt = blockIdx.x, nt = blockIdx.y, z = blockIdx.z;
  const u16* A = (z==4) ? DWbf : Xbf;
  const u16* B = (z==0)?WtQ:(z==1)?WtK:(z==2)?WtV:(z==3)?WtCO:WtPW;
  const float* bias = (z==0)?bq:(z==1)?bk_:(z==2)?bv:(z==3)?bco:bcv;

  char* La = smem; char* Lb = smem + 16384;
  int m0 = mt*128, n0 = nt*128;

  f32x4 zero = {0.f,0.f,0.f,0.f};
  f32x4 acc[4][4];
  #pragma unroll
  for (int i=0;i<4;i++)
    #pragma unroll
    for (int j=0;j<4;j++) acc[i][j] = zero;

  int rr = w*8 + (l>>3);
  int ch = l&7;

  for (int kt=0; kt<12; kt++){
    #pragma unroll
    for (int i=0;i<4;i++){
      int row = i*32 + rr;
      int sc = ch ^ (row&7);
      gload_lds16(A + (size_t)(m0+row)*C_IN + kt*64 + sc*8, La + i*4096 + w*1024);
      gload_lds16(B + (size_t)(n0+row)*C_IN + kt*64 + sc*8, Lb + i*4096 + w*1024);
    }
    __syncthreads();
    bf16x8 af[4][2], bfr[4][2];
    #pragma unroll
    for (int mi=0;mi<4;mi++){
      int row = wr*64 + mi*16 + c;
      #pragma unroll
      for (int kk=0;kk<2;kk++){
        int sw = (kk*4+g) ^ (row&7);
        af[mi][kk] = *(const bf16x8*)(La + row*128 + sw*16);
      }
    }
    #pragma unroll
    for (int ni=0;ni<4;ni++){
      int row = wc*64 + ni*16 + c;
      #pragma unroll
      for (int kk=0;kk<2;kk++){
        int sw = (kk*4+g) ^ (row&7);
        bfr[ni][kk] = *(const bf16x8*)(Lb + row*128 + sw*16);
      }
    }
    #pragma unroll
    for (int kk=0;kk<2;kk++)
      #pragma unroll
      for (int mi=0;mi<4;mi++)
        #pragma unroll
        for (int ni=0;ni<4;ni++)
          acc[mi][ni] = __builtin_amdgcn_mfma_f32_16x16x32_bf16(af[mi][kk], bfr[ni][kk], acc[mi][ni], 0,0,0);
    __syncthreads();
  }

  if (z == 2){
    #pragma unroll
    for (int ni=0;ni<4;ni++){
      int col = n0 + wc*64 + ni*16 + c;
      float bvv = bias[col];
      int hh = col>>6, d = col&63;
      #pragma unroll
      for (int mi=0;mi<4;mi++)
        #pragma unroll
        for (int r=0;r<4;r++){
          int rowg = m0 + wr*64 + mi*16 + g*4 + r;
          int bb = rowg>>11, s = rowg&2047;
          Vt[((size_t)((bb*NH+hh)*HD + d))*BSEQ + s] = f2b(acc[mi][ni][r] + bvv);
        }
    }
  } else {
    u16* O = (z==0)?Qo:(z==1)?Ko:(z==3)?COo:KCo;
    #pragma unroll
    for (int ni=0;ni<4;ni++){
      int col = n0 + wc*64 + ni*16 + c;
      float bvv = bias[col];
      #pragma unroll
      for (int mi=0;mi<4;mi++)
        #pragma unroll
        for (int r=0;r<4;r++){
          int rowg = m0 + wr*64 + mi*16 + g*4 + r;
          O[(size_t)rowg*AHS + col] = f2b(acc[mi][ni][r] + bvv);
        }
    }
  }
}

// ---------------- span kernel logits + softmax over 9 taps ----------------
__global__ __launch_bounds__(64) void k_ck(const u16* __restrict__ Qb, const u16* __restrict__ KCb,
    const u16* __restrict__ WckT, const float* __restrict__ bck, float* __restrict__ ckp)
{
  int row = blockIdx.x, l = threadIdx.x;
  __shared__ float ca[AHS];
  __shared__ float lg[NH*KK9];
  const u16* qr = Qb + (size_t)row*AHS;
  const u16* kr = KCb + (size_t)row*AHS;
  for (int j=l; j<AHS; j+=64) ca[j] = b2f(qr[j]) * b2f(kr[j]);
  __syncthreads();
  if (l < NH*KK9){
    const u16* wr = WckT + l*AHS;
    float acc = bck[l];
    for (int k=0;k<AHS;k+=8){
      bf16x8 wv = *(const bf16x8*)(wr + k);
      #pragma unroll
      for (int j=0;j<8;j++) acc += ca[k+j]*b2f((u16)wv[j]);
    }
    lg[l] = acc;
  }
  __syncthreads();
  if (l < NH*KK9){
    int h = l/KK9, b0 = h*KK9;
    float m = lg[b0];
    #pragma unroll
    for (int j=1;j<KK9;j++) m = fmaxf(m, lg[b0+j]);
    float s = 0.f;
    #pragma unroll
    for (int j=0;j<KK9;j++) s += __expf(lg[b0+j]-m);
    ckp[(size_t)row*(NH*KK9) + l] = __expf(lg[l]-m)/s;
  }
}

// ---------------- dynamic conv output (unfold x ck), writes out[:,:,384:768] ----------------
__global__ __launch_bounds__(384) void k_convout(const u16* __restrict__ CO, const float* __restrict__ ckp,
                                                 float* __restrict__ out)
{
  int blk = blockIdx.x; int b = blk>>11, s = blk&2047;
  int c = threadIdx.x; int h = c>>6;
  __shared__ float ck[NH*KK9];
  if (c < NH*KK9) ck[c] = ckp[(size_t)blk*(NH*KK9) + c];
  __syncthreads();
  float acc = 0.f;
  #pragma unroll
  for (int k=0;k<KK9;k++){
    int ss = s + k - 4;
    if ((unsigned)ss < 2048u)
      acc += b2f(CO[(size_t)((b<<11)+ss)*AHS + c]) * ck[h*KK9+k];
  }
  out[(size_t)blk*(2*AHS) + AHS + c] = acc;
}

// ---------------- flash attention, writes out[:,:,0:384] ----------------
__global__ __launch_bounds__(256) void k_attn(const u16* __restrict__ Qb, const u16* __restrict__ Kb,
    const u16* __restrict__ Vt, const float* __restrict__ amask, const float* __restrict__ hmask,
    float* __restrict__ out)
{
  __shared__ char smem[49152]; // K dbuf 16K | V dbuf 16K | P per-wave 16K
  int tid = threadIdx.x, l = tid&63, w = tid>>6;
  int g = l>>4, c = l&15;
  int qt = blockIdx.x, bh = blockIdx.y;
  int b = bh/NH, h = bh - b*NH;

  char* Kls = smem;
  char* Vls = smem + 16384;
  char* Pls = smem + 32768 + w*4096;

  bf16x8 aq[2][2];
  int q0 = qt*128 + w*32;
  #pragma unroll
  for (int mi=0;mi<2;mi++)
    #pragma unroll
    for (int kk=0;kk<2;kk++)
      aq[mi][kk] = *(const bf16x8*)(Qb + (size_t)(b*BSEQ + q0 + mi*16 + c)*AHS + h*HD + kk*32 + g*8);

  f32x4 zero = {0.f,0.f,0.f,0.f};
  f32x4 o[2][4];
  #pragma unroll
  for (int i=0;i<2;i++)
    #pragma unroll
    for (int j=0;j<4;j++) o[i][j] = zero;
  float lsum[2][4] = {{0,0,0,0},{0,0,0,0}};

  int rr = w*8 + (l>>3), ch = l&7;

  // prologue stage t=0 into buffer 0
  #pragma unroll
  for (int i=0;i<2;i++){
    int row = i*32 + rr; int sc = ch ^ (row&7);
    gload_lds16(Kb + (size_t)(b*BSEQ + row)*AHS + h*HD + sc*8, Kls + i*4096 + w*1024);
    gload_lds16(Vt + (size_t)(bh*HD + row)*BSEQ + sc*8,        Vls + i*4096 + w*1024);
  }
  __syncthreads();

  for (int t=0;t<32;t++){
    int p = t&1;
    if (t < 31){
      int tn = t+1;
      #pragma unroll
      for (int i=0;i<2;i++){
        int row = i*32 + rr; int sc = ch ^ (row&7);
        gload_lds16(Kb + (size_t)(b*BSEQ + tn*64 + row)*AHS + h*HD + sc*8, Kls + (p^1)*8192 + i*4096 + w*1024);
        gload_lds16(Vt + (size_t)(bh*HD + row)*BSEQ + tn*64 + sc*8,        Vls + (p^1)*8192 + i*4096 + w*1024);
      }
    }
    // QK^T
    bf16x8 kf[4][2];
    #pragma unroll
    for (int ni=0;ni<4;ni++){
      int row = ni*16 + c;
      #pragma unroll
      for (int kk=0;kk<2;kk++){
        int sw = (kk*4+g) ^ (row&7);
        kf[ni][kk] = *(const bf16x8*)(Kls + p*8192 + row*128 + sw*16);
      }
    }
    float pv[2][4][4];
    #pragma unroll
    for (int mi=0;mi<2;mi++)
      #pragma unroll
      for (int ni=0;ni<4;ni++){
        f32x4 s4 = zero;
        s4 = __builtin_amdgcn_mfma_f32_16x16x32_bf16(aq[mi][0], kf[ni][0], s4, 0,0,0);
        s4 = __builtin_amdgcn_mfma_f32_16x16x32_bf16(aq[mi][1], kf[ni][1], s4, 0,0,0);
        float mk = amask[b*BSEQ + t*64 + ni*16 + c];
        #pragma unroll
        for (int r=0;r<4;r++) pv[mi][ni][r] = __expf(s4[r]*0.125f + mk);
      }
    // row sums (scores bounded; max-free online softmax)
    #pragma unroll
    for (int mi=0;mi<2;mi++)
      #pragma unroll
      for (int r=0;r<4;r++){
        float rs = pv[mi][0][r]+pv[mi][1][r]+pv[mi][2][r]+pv[mi][3][r];
        rs += __shfl_xor(rs, 1);
        rs += __shfl_xor(rs, 2);
        rs += __shfl_xor(rs, 4);
        rs += __shfl_xor(rs, 8);
        lsum[mi][r] += rs;
      }
    // write P to LDS (swizzled), transpose C-layout -> A-layout
    #pragma unroll
    for (int mi=0;mi<2;mi++)
      #pragma unroll
      for (int ni=0;ni<4;ni++){
        int colb = ni*16 + c;
        #pragma unroll
        for (int r=0;r<4;r++){
          int row = mi*16 + g*4 + r;
          int swc = (colb>>3) ^ (row&7);
          *(u16*)(Pls + row*128 + swc*16 + (colb&7)*2) = f2b(pv[mi][ni][r]);
        }
      }
    // PV
    bf16x8 pa[2][2];
    #pragma unroll
    for (int mf=0; mf<2; mf++){
      int row = mf*16 + c;
      #pragma unroll
      for (int kk=0;kk<2;kk++){
        int sw = (kk*4+g) ^ (row&7);
        pa[mf][kk] = *(const bf16x8*)(Pls + row*128 + sw*16);
      }
    }
    bf16x8 vf[4][2];
    #pragma unroll
    for (int di=0;di<4;di++){
      int row = di*16 + c;
      #pragma unroll
      for (int kk=0;kk<2;kk++){
        int sw = (kk*4+g) ^ (row&7);
        vf[di][kk] = *(const bf16x8*)(Vls + p*8192 + row*128 + sw*16);
      }
    }
    #pragma unroll
    for (int kk=0;kk<2;kk++)
      #pragma unroll
      for (int mi=0;mi<2;mi++)
        #pragma unroll
        for (int di=0;di<4;di++)
          o[mi][di] = __builtin_amdgcn_mfma_f32_16x16x32_bf16(pa[mi][kk], vf[di][kk], o[mi][di], 0,0,0);
    __syncthreads();
  }

  float hm = hmask[h];
  #pragma unroll
  for (int mi=0;mi<2;mi++)
    #pragma unroll
    for (int di=0;di<4;di++)
      #pragma unroll
      for (int r=0;r<4;r++){
        int row = q0 + mi*16 + g*4 + r;
        out[(size_t)(b*BSEQ + row)*(2*AHS) + h*HD + di*16 + c] = o[mi][di][r] / lsum[mi][r] * hm;
      }
}

extern "C" void kernel_launch(void* const* d_in, const int* in_sizes, int n_in,
                              void* d_out, int out_size, void* d_ws, size_t ws_size,
                              hipStream_t stream) {
  (void)in_sizes; (void)n_in; (void)out_size; (void)ws_size;
  const float* X     = (const float*)d_in[0];
  const float* amask = (const float*)d_in[1];
  const float* hmask = (const float*)d_in[2];
  const float* Wq  = (const float*)d_in[3];
  const float* bq  = (const float*)d_in[4];
  const float* Wk  = (const float*)d_in[5];
  const float* bk  = (const float*)d_in[6];
  const float* Wv  = (const float*)d_in[7];
  const float* bv  = (const float*)d_in[8];
  const float* dwk = (const float*)d_in[9];
  const float* pw  = (const float*)d_in[10];
  const float* cb  = (const float*)d_in[11];
  const float* Wck = (const float*)d_in[12];
  const float* bck = (const float*)d_in[13];
  const float* Wco = (const float*)d_in[14];
  const float* bco = (const float*)d_in[15];
  float* out = (float*)d_out;

  char* p = (char*)d_ws;
  u16* XBF  = (u16*)p; p += (size_t)MTOT*C_IN*2;
  u16* DWBF = (u16*)p; p += (size_t)MTOT*C_IN*2;
  u16* WTQ  = (u16*)p; p += (size_t)C_IN*AHS*2;
  u16* WTK  = (u16*)p; p += (size_t)C_IN*AHS*2;
  u16* WTV  = (u16*)p; p += (size_t)C_IN*AHS*2;
  u16* WTCO = (u16*)p; p += (size_t)C_IN*AHS*2;
  u16* WTPW = (u16*)p; p += (size_t)C_IN*AHS*2;
  u16* WCKT = (u16*)p; p += (size_t)(NH*KK9)*AHS*2;
  u16* QB   = (u16*)p; p += (size_t)MTOT*AHS*2;
  u16* KB   = (u16*)p; p += (size_t)MTOT*AHS*2;
  u16* COB  = (u16*)p; p += (size_t)MTOT*AHS*2;
  u16* KCB  = (u16*)p; p += (size_t)MTOT*AHS*2;
  u16* VT   = (u16*)p; p += (size_t)MTOT*AHS*2;
  float* CKP = (float*)p; p += (size_t)MTOT*(NH*KK9)*4;

  dim3 tb(32,8);
  k_transpose_cast<<<dim3(24,12),tb,0,stream>>>(Wq,  WTQ,  C_IN, AHS);
  k_transpose_cast<<<dim3(24,12),tb,0,stream>>>(Wk,  WTK,  C_IN, AHS);
  k_transpose_cast<<<dim3(24,12),tb,0,stream>>>(Wv,  WTV,  C_IN, AHS);
  k_transpose_cast<<<dim3(24,12),tb,0,stream>>>(Wco, WTCO, C_IN, AHS);
  k_transpose_cast<<<dim3(24,12),tb,0,stream>>>(pw,  WTPW, C_IN, AHS);
  k_transpose_cast<<<dim3(12,2), tb,0,stream>>>(Wck, WCKT, AHS, NH*KK9);

  k_prep_x<<<MTOT,192,0,stream>>>(X, dwk, XBF, DWBF);

  k_gemm5<<<dim3(64,3,5),256,0,stream>>>(XBF, DWBF, WTQ, WTK, WTV, WTCO, WTPW,
                                         bq, bk, bv, bco, cb,
                                         QB, KB, VT, COB, KCB);

  k_ck<<<MTOT,64,0,stream>>>(QB, KCB, WCKT, bck, CKP);
  k_convout<<<MTOT,384,0,stream>>>(COB, CKP, out);
  k_attn<<<dim3(16,24),256,0,stream>>>(QB, KB, VT, amask, hmask, out);
}

// Round 2
// 217.427 us; speedup vs baseline: 1.1457x; 1.1457x over previous
//
#include <hip/hip_runtime.h>
#include <hip/hip_bf16.h>
#include <stdint.h>

typedef unsigned short u16;
typedef short bf16x8 __attribute__((ext_vector_type(8)));
typedef float f32x4 __attribute__((ext_vector_type(4)));

#define C_IN 768
#define AHS 384
#define NH 6
#define HD 64
#define KK9 9
#define BSEQ 2048
#define MTOT 8192

__device__ __forceinline__ float b2f(u16 u){
  union { unsigned u; float f; } v; v.u = ((unsigned)u) << 16; return v.f;
}
__device__ __forceinline__ u16 f2b(float f){
  union { float f; unsigned u; } v; v.f = f;
  unsigned r = (v.u + 0x7FFFu + ((v.u >> 16) & 1u)) >> 16;
  return (u16)r;
}
__device__ __forceinline__ void gload_lds16(const void* g, void* l){
  __builtin_amdgcn_global_load_lds((const __attribute__((address_space(1))) unsigned int*)g,
                                   (__attribute__((address_space(3))) unsigned int*)l, 16, 0, 0);
}

// ---------------- transpose + cast f32[R][C] -> bf16[C][R], 5 weights fused ----------------
__global__ void k_transpose_cast5(const float* __restrict__ s0, const float* __restrict__ s1,
                                  const float* __restrict__ s2, const float* __restrict__ s3,
                                  const float* __restrict__ s4,
                                  u16* __restrict__ d0, u16* __restrict__ d1, u16* __restrict__ d2,
                                  u16* __restrict__ d3, u16* __restrict__ d4){
  __shared__ float t[32][33];
  int z = blockIdx.z;
  const float* src = (z==0)?s0:(z==1)?s1:(z==2)?s2:(z==3)?s3:s4;
  u16* dst = (z==0)?d0:(z==1)?d1:(z==2)?d2:(z==3)?d3:d4;
  const int R = C_IN, C = AHS;
  int r0 = blockIdx.x*32, c0 = blockIdx.y*32;
  int tx = threadIdx.x, ty = threadIdx.y;
  #pragma unroll
  for (int j=0;j<4;j++){
    int r = r0 + ty + j*8, c = c0 + tx;
    t[ty+j*8][tx] = src[(size_t)r*C + c];
  }
  __syncthreads();
  #pragma unroll
  for (int j=0;j<4;j++){
    int c = c0 + ty + j*8, r = r0 + tx;
    dst[(size_t)c*R + r] = f2b(t[tx][ty+j*8]);
  }
}

__global__ void k_transpose_cast(const float* __restrict__ src, u16* __restrict__ dst, int R, int C){
  __shared__ float t[32][33];
  int r0 = blockIdx.x*32, c0 = blockIdx.y*32;
  int tx = threadIdx.x, ty = threadIdx.y;
  #pragma unroll
  for (int j=0;j<4;j++){
    int r = r0 + ty + j*8, c = c0 + tx;
    t[ty+j*8][tx] = (r<R && c<C) ? src[(size_t)r*C + c] : 0.f;
  }
  __syncthreads();
  #pragma unroll
  for (int j=0;j<4;j++){
    int c = c0 + ty + j*8, r = r0 + tx;
    if (r<R && c<C) dst[(size_t)c*R + r] = f2b(t[tx][ty+j*8]);
  }
}

// ---------------- X cast + depthwise conv (SAME, per batch) ----------------
__global__ __launch_bounds__(192) void k_prep_x(const float* __restrict__ X, const float* __restrict__ dwk,
                          u16* __restrict__ Xbf, u16* __restrict__ DWbf){
  int blk = blockIdx.x; int b = blk>>11; int s = blk&2047;
  int c0 = threadIdx.x*4;
  size_t base = (size_t)blk*C_IN + c0;
  float4 xc = *(const float4*)(X + base);
  *(ushort4*)(Xbf + base) = make_ushort4(f2b(xc.x), f2b(xc.y), f2b(xc.z), f2b(xc.w));
  float a0=0.f,a1=0.f,a2=0.f,a3=0.f;
  #pragma unroll
  for (int k=0;k<KK9;k++){
    int ss = s + k - 4;
    if ((unsigned)ss < 2048u){
      float4 xv = *(const float4*)(X + ((size_t)((b<<11)+ss)*C_IN + c0));
      float4 wv = *(const float4*)(dwk + k*C_IN + c0);
      a0 += xv.x*wv.x; a1 += xv.y*wv.y; a2 += xv.z*wv.z; a3 += xv.w*wv.w;
    }
  }
  *(ushort4*)(DWbf + base) = make_ushort4(f2b(a0), f2b(a1), f2b(a2), f2b(a3));
}

// ---------------- 5-way fused projection GEMM: [8192,768]x[768,384] ----------------
// z: 0=Q 1=K 2=V(-> transposed Vt[bh][d][s]) 3=CO 4=KeyConv(A=DW, B=pw)
__global__ __launch_bounds__(256) void k_gemm5(
    const u16* __restrict__ Xbf, const u16* __restrict__ DWbf,
    const u16* __restrict__ WtQ, const u16* __restrict__ WtK, const u16* __restrict__ WtV,
    const u16* __restrict__ WtCO, const u16* __restrict__ WtPW,
    const float* __restrict__ bq, const float* __restrict__ bk_, const float* __restrict__ bv,
    const float* __restrict__ bco, const float* __restrict__ bcv,
    u16* __restrict__ Qo, u16* __restrict__ Ko, u16* __restrict__ Vt,
    u16* __restrict__ COo, u16* __restrict__ KCo)
{
  __shared__ char smem[32768];
  int tid = threadIdx.x, l = tid&63, w = tid>>6;
  int g = l>>4, c = l&15;
  int wr = w>>1, wc = w&1;
  int mt = blockIdx.x, nt = blockIdx.y, z = blockIdx.z;
  const u16* A = (z==4) ? DWbf : Xbf;
  const u16* B = (z==0)?WtQ:(z==1)?WtK:(z==2)?WtV:(z==3)?WtCO:WtPW;
  const float* bias = (z==0)?bq:(z==1)?bk_:(z==2)?bv:(z==3)?bco:bcv;

  char* La = smem; char* Lb = smem + 16384;
  int m0 = mt*128, n0 = nt*128;

  f32x4 zero = {0.f,0.f,0.f,0.f};
  f32x4 acc[4][4];
  #pragma unroll
  for (int i=0;i<4;i++)
    #pragma unroll
    for (int j=0;j<4;j++) acc[i][j] = zero;

  int rr = w*8 + (l>>3);
  int ch = l&7;

  for (int kt=0; kt<12; kt++){
    #pragma unroll
    for (int i=0;i<4;i++){
      int row = i*32 + rr;
      int sc = ch ^ (row&7);
      gload_lds16(A + (size_t)(m0+row)*C_IN + kt*64 + sc*8, La + i*4096 + w*1024);
      gload_lds16(B + (size_t)(n0+row)*C_IN + kt*64 + sc*8, Lb + i*4096 + w*1024);
    }
    __syncthreads();
    bf16x8 af[4][2], bfr[4][2];
    #pragma unroll
    for (int mi=0;mi<4;mi++){
      int row = wr*64 + mi*16 + c;
      #pragma unroll
      for (int kk=0;kk<2;kk++){
        int sw = (kk*4+g) ^ (row&7);
        af[mi][kk] = *(const bf16x8*)(La + row*128 + sw*16);
      }
    }
    #pragma unroll
    for (int ni=0;ni<4;ni++){
      int row = wc*64 + ni*16 + c;
      #pragma unroll
      for (int kk=0;kk<2;kk++){
        int sw = (kk*4+g) ^ (row&7);
        bfr[ni][kk] = *(const bf16x8*)(Lb + row*128 + sw*16);
      }
    }
    #pragma unroll
    for (int kk=0;kk<2;kk++)
      #pragma unroll
      for (int mi=0;mi<4;mi++)
        #pragma unroll
        for (int ni=0;ni<4;ni++)
          acc[mi][ni] = __builtin_amdgcn_mfma_f32_16x16x32_bf16(af[mi][kk], bfr[ni][kk], acc[mi][ni], 0,0,0);
    __syncthreads();
  }

  if (z == 2){
    #pragma unroll
    for (int ni=0;ni<4;ni++){
      int col = n0 + wc*64 + ni*16 + c;
      float bvv = bias[col];
      int hh = col>>6, d = col&63;
      #pragma unroll
      for (int mi=0;mi<4;mi++){
        int rowg = m0 + wr*64 + mi*16 + g*4;
        int bb = rowg>>11, s = rowg&2047;
        ushort4 pk = make_ushort4(f2b(acc[mi][ni][0] + bvv), f2b(acc[mi][ni][1] + bvv),
                                  f2b(acc[mi][ni][2] + bvv), f2b(acc[mi][ni][3] + bvv));
        *(ushort4*)(Vt + ((size_t)((bb*NH+hh)*HD + d))*BSEQ + s) = pk;
      }
    }
  } else {
    u16* O = (z==0)?Qo:(z==1)?Ko:(z==3)?COo:KCo;
    #pragma unroll
    for (int ni=0;ni<4;ni++){
      int col = n0 + wc*64 + ni*16 + c;
      float bvv = bias[col];
      #pragma unroll
      for (int mi=0;mi<4;mi++)
        #pragma unroll
        for (int r=0;r<4;r++){
          int rowg = m0 + wr*64 + mi*16 + g*4 + r;
          O[(size_t)rowg*AHS + col] = f2b(acc[mi][ni][r] + bvv);
        }
    }
  }
}

// ---------------- span kernel logits + softmax over 9 taps ----------------
__global__ __launch_bounds__(64) void k_ck(const u16* __restrict__ Qb, const u16* __restrict__ KCb,
    const u16* __restrict__ WckT, const float* __restrict__ bck, float* __restrict__ ckp)
{
  int row = blockIdx.x, l = threadIdx.x;
  __shared__ float ca[AHS];
  __shared__ float lg[NH*KK9];
  const u16* qr = Qb + (size_t)row*AHS;
  const u16* kr = KCb + (size_t)row*AHS;
  for (int j=l; j<AHS; j+=64) ca[j] = b2f(qr[j]) * b2f(kr[j]);
  __syncthreads();
  if (l < NH*KK9){
    const u16* wr = WckT + l*AHS;
    float acc = bck[l];
    for (int k=0;k<AHS;k+=8){
      bf16x8 wv = *(const bf16x8*)(wr + k);
      #pragma unroll
      for (int j=0;j<8;j++) acc += ca[k+j]*b2f((u16)wv[j]);
    }
    lg[l] = acc;
  }
  __syncthreads();
  if (l < NH*KK9){
    int h = l/KK9, b0 = h*KK9;
    float m = lg[b0];
    #pragma unroll
    for (int j=1;j<KK9;j++) m = fmaxf(m, lg[b0+j]);
    float s = 0.f;
    #pragma unroll
    for (int j=0;j<KK9;j++) s += __expf(lg[b0+j]-m);
    ckp[(size_t)row*(NH*KK9) + l] = __expf(lg[l]-m)/s;
  }
}

// ---------------- dynamic conv output (unfold x ck), writes out[:,:,384:768] ----------------
// 4 sequence positions per block, 96 lanes x 4 channels each
__global__ __launch_bounds__(384) void k_convout(const u16* __restrict__ CO, const float* __restrict__ ckp,
                                                 float* __restrict__ out)
{
  int tid = threadIdx.x;
  int pos = tid/96, lane96 = tid - pos*96;
  int sIdx = blockIdx.x*4 + pos;
  int b = sIdx>>11, s = sIdx&2047;
  int cc = lane96*4, h = cc>>6;
  __shared__ float ck[4][NH*KK9];
  if (lane96 < NH*KK9) ck[pos][lane96] = ckp[(size_t)sIdx*(NH*KK9) + lane96];
  __syncthreads();
  float a0=0.f,a1=0.f,a2=0.f,a3=0.f;
  #pragma unroll
  for (int k=0;k<KK9;k++){
    int ss = s + k - 4;
    if ((unsigned)ss < 2048u){
      ushort4 v = *(const ushort4*)(CO + ((size_t)((b<<11)+ss)*AHS + cc));
      float wk = ck[pos][h*KK9+k];
      a0 += b2f(v.x)*wk; a1 += b2f(v.y)*wk; a2 += b2f(v.z)*wk; a3 += b2f(v.w)*wk;
    }
  }
  float4 r = make_float4(a0,a1,a2,a3);
  *(float4*)(out + (size_t)sIdx*(2*AHS) + AHS + cc) = r;
}

// ---------------- flash attention, writes out[:,:,0:384] ----------------
// q-tile = 64 rows, 4 waves x 16 rows each; KV tile = 64, double-buffered
__global__ __launch_bounds__(256) void k_attn(const u16* __restrict__ Qb, const u16* __restrict__ Kb,
    const u16* __restrict__ Vt, const float* __restrict__ amask, const float* __restrict__ hmask,
    float* __restrict__ out)
{
  __shared__ char smem[40960]; // K dbuf 16K | V dbuf 16K | P per-wave 2K x 4
  int tid = threadIdx.x, l = tid&63, w = tid>>6;
  int g = l>>4, c = l&15;
  int qt = blockIdx.x, bh = blockIdx.y;
  int b = bh/NH, h = bh - b*NH;

  char* Kls = smem;
  char* Vls = smem + 16384;
  char* Pls = smem + 32768 + w*2048;

  bf16x8 aq[2];
  int q0 = qt*64 + w*16;
  #pragma unroll
  for (int kk=0;kk<2;kk++)
    aq[kk] = *(const bf16x8*)(Qb + (size_t)(b*BSEQ + q0 + c)*AHS + h*HD + kk*32 + g*8);

  f32x4 zero = {0.f,0.f,0.f,0.f};
  f32x4 o[4];
  #pragma unroll
  for (int j=0;j<4;j++) o[j] = zero;
  float lsum[4] = {0,0,0,0};

  int rr = w*8 + (l>>3), ch = l&7;
  const float LOG2E = 1.4426950408889634f;
  const float SCL = 0.18033688011112042f; // 0.125 * log2(e)

  // prologue stage t=0 into buffer 0
  #pragma unroll
  for (int i=0;i<2;i++){
    int row = i*32 + rr; int sc = ch ^ (row&7);
    gload_lds16(Kb + (size_t)(b*BSEQ + row)*AHS + h*HD + sc*8, Kls + i*4096 + w*1024);
    gload_lds16(Vt + (size_t)(bh*HD + row)*BSEQ + sc*8,        Vls + i*4096 + w*1024);
  }
  __syncthreads();

  for (int t=0;t<32;t++){
    int p = t&1;
    if (t < 31){
      int tn = t+1;
      #pragma unroll
      for (int i=0;i<2;i++){
        int row = i*32 + rr; int sc = ch ^ (row&7);
        gload_lds16(Kb + (size_t)(b*BSEQ + tn*64 + row)*AHS + h*HD + sc*8, Kls + (p^1)*8192 + i*4096 + w*1024);
        gload_lds16(Vt + (size_t)(bh*HD + row)*BSEQ + tn*64 + sc*8,        Vls + (p^1)*8192 + i*4096 + w*1024);
      }
    }
    // QK^T (clustered MFMA)
    bf16x8 kf[4][2];
    #pragma unroll
    for (int ni=0;ni<4;ni++){
      int row = ni*16 + c;
      #pragma unroll
      for (int kk=0;kk<2;kk++){
        int sw = (kk*4+g) ^ (row&7);
        kf[ni][kk] = *(const bf16x8*)(Kls + p*8192 + row*128 + sw*16);
      }
    }
    f32x4 sc4[4];
    __builtin_amdgcn_s_setprio(1);
    #pragma unroll
    for (int ni=0;ni<4;ni++){
      sc4[ni] = zero;
      sc4[ni] = __builtin_amdgcn_mfma_f32_16x16x32_bf16(aq[0], kf[ni][0], sc4[ni], 0,0,0);
      sc4[ni] = __builtin_amdgcn_mfma_f32_16x16x32_bf16(aq[1], kf[ni][1], sc4[ni], 0,0,0);
    }
    __builtin_amdgcn_s_setprio(0);
    float pv[4][4];
    #pragma unroll
    for (int ni=0;ni<4;ni++){
      float mkl = amask[b*BSEQ + t*64 + ni*16 + c] * LOG2E;
      #pragma unroll
      for (int r=0;r<4;r++) pv[ni][r] = exp2f(fmaf(sc4[ni][r], SCL, mkl));
    }
    // row sums (scores bounded; max-free online softmax)
    #pragma unroll
    for (int r=0;r<4;r++){
      float rs = pv[0][r]+pv[1][r]+pv[2][r]+pv[3][r];
      rs += __shfl_xor(rs, 1);
      rs += __shfl_xor(rs, 2);
      rs += __shfl_xor(rs, 4);
      rs += __shfl_xor(rs, 8);
      lsum[r] += rs;
    }
    // write P to LDS (swizzled), transpose C-layout -> A-layout
    #pragma unroll
    for (int ni=0;ni<4;ni++){
      int colb = ni*16 + c;
      #pragma unroll
      for (int r=0;r<4;r++){
        int row = g*4 + r;
        int swc = (colb>>3) ^ (row&7);
        *(u16*)(Pls + row*128 + swc*16 + (colb&7)*2) = f2b(pv[ni][r]);
      }
    }
    // PV
    bf16x8 pa[2];
    {
      int row = c;
      #pragma unroll
      for (int kk=0;kk<2;kk++){
        int sw = (kk*4+g) ^ (row&7);
        pa[kk] = *(const bf16x8*)(Pls + row*128 + sw*16);
      }
    }
    bf16x8 vf[4][2];
    #pragma unroll
    for (int di=0;di<4;di++){
      int row = di*16 + c;
      #pragma unroll
      for (int kk=0;kk<2;kk++){
        int sw = (kk*4+g) ^ (row&7);
        vf[di][kk] = *(const bf16x8*)(Vls + p*8192 + row*128 + sw*16);
      }
    }
    __builtin_amdgcn_s_setprio(1);
    #pragma unroll
    for (int kk=0;kk<2;kk++)
      #pragma unroll
      for (int di=0;di<4;di++)
        o[di] = __builtin_amdgcn_mfma_f32_16x16x32_bf16(pa[kk], vf[di][kk], o[di], 0,0,0);
    __builtin_amdgcn_s_setprio(0);
    __syncthreads();
  }

  float hm = hmask[h];
  #pragma unroll
  for (int di=0;di<4;di++)
    #pragma unroll
    for (int r=0;r<4;r++){
      int row = q0 + g*4 + r;
      out[(size_t)(b*BSEQ + row)*(2*AHS) + h*HD + di*16 + c] = o[di][r] / lsum[r] * hm;
    }
}

extern "C" void kernel_launch(void* const* d_in, const int* in_sizes, int n_in,
                              void* d_out, int out_size, void* d_ws, size_t ws_size,
                              hipStream_t stream) {
  (void)in_sizes; (void)n_in; (void)out_size; (void)ws_size;
  const float* X     = (const float*)d_in[0];
  const float* amask = (const float*)d_in[1];
  const float* hmask = (const float*)d_in[2];
  const float* Wq  = (const float*)d_in[3];
  const float* bq  = (const float*)d_in[4];
  const float* Wk  = (const float*)d_in[5];
  const float* bk  = (const float*)d_in[6];
  const float* Wv  = (const float*)d_in[7];
  const float* bv  = (const float*)d_in[8];
  const float* dwk = (const float*)d_in[9];
  const float* pw  = (const float*)d_in[10];
  const float* cb  = (const float*)d_in[11];
  const float* Wck = (const float*)d_in[12];
  const float* bck = (const float*)d_in[13];
  const float* Wco = (const float*)d_in[14];
  const float* bco = (const float*)d_in[15];
  float* out = (float*)d_out;

  char* p = (char*)d_ws;
  u16* XBF  = (u16*)p; p += (size_t)MTOT*C_IN*2;
  u16* DWBF = (u16*)p; p += (size_t)MTOT*C_IN*2;
  u16* WTQ  = (u16*)p; p += (size_t)C_IN*AHS*2;
  u16* WTK  = (u16*)p; p += (size_t)C_IN*AHS*2;
  u16* WTV  = (u16*)p; p += (size_t)C_IN*AHS*2;
  u16* WTCO = (u16*)p; p += (size_t)C_IN*AHS*2;
  u16* WTPW = (u16*)p; p += (size_t)C_IN*AHS*2;
  u16* WCKT = (u16*)p; p += (size_t)(NH*KK9)*AHS*2;
  u16* QB   = (u16*)p; p += (size_t)MTOT*AHS*2;
  u16* KB   = (u16*)p; p += (size_t)MTOT*AHS*2;
  u16* COB  = (u16*)p; p += (size_t)MTOT*AHS*2;
  u16* KCB  = (u16*)p; p += (size_t)MTOT*AHS*2;
  u16* VT   = (u16*)p; p += (size_t)MTOT*AHS*2;
  float* CKP = (float*)p; p += (size_t)MTOT*(NH*KK9)*4;

  dim3 tb(32,8);
  k_transpose_cast5<<<dim3(24,12,5),tb,0,stream>>>(Wq, Wk, Wv, Wco, pw, WTQ, WTK, WTV, WTCO, WTPW);
  k_transpose_cast<<<dim3(12,2), tb,0,stream>>>(Wck, WCKT, AHS, NH*KK9);

  k_prep_x<<<MTOT,192,0,stream>>>(X, dwk, XBF, DWBF);

  k_gemm5<<<dim3(64,3,5),256,0,stream>>>(XBF, DWBF, WTQ, WTK, WTV, WTCO, WTPW,
                                         bq, bk, bv, bco, cb,
                                         QB, KB, VT, COB, KCB);

  k_ck<<<MTOT,64,0,stream>>>(QB, KCB, WCKT, bck, CKP);
  k_convout<<<2048,384,0,stream>>>(COB, CKP, out);
  k_attn<<<dim3(32,24),256,0,stream>>>(QB, KB, VT, amask, hmask, out);
}